// Round 6
// baseline (162.704 us; speedup 1.0000x reference)
//
#include <hip/hip_runtime.h>

#define N_   8192
#define FIN  256
#define FOUT 128
#define NW   (N_ / 32)   // bitmask words per row = 256

typedef _Float16 f16x8 __attribute__((ext_vector_type(8)));
typedef float    f32x4 __attribute__((ext_vector_type(4)));
typedef unsigned int uint;

// LDS-only barrier: orders LDS without draining vmcnt.
#define LDS_BARRIER() asm volatile("s_waitcnt lgkmcnt(0)\n\ts_barrier" ::: "memory")

// ---------------- Kernel 0: pack adj (int32 0/1) -> bitmask, 32 j per word ---
// One wave per row; 32 iterations of 256 j. Lane l reads int4 at j=4l (1 KB
// coalesced per wave-load), packs 4 bits, shfl_xor tree -> lanes l%8==0 hold
// one j-ordered u32 word. Pure HBM streamer: 256 MB read, 8 MB write.
__global__ __launch_bounds__(256) void k_pack(
    const int* __restrict__ adj, uint* __restrict__ bm)
{
    const int wid = (blockIdx.x * 256 + threadIdx.x) >> 6;   // row 0..8191
    const int l   = threadIdx.x & 63;
    const int4* __restrict__ arow = (const int4*)(adj + (size_t)wid * N_);
    uint* __restrict__ brow = bm + (size_t)wid * NW;

    #pragma unroll 2
    for (int jb = 0; jb < 32; ++jb) {
        int4 av = arow[jb * 64 + l];
        uint nib = (uint)(av.x != 0) | ((uint)(av.y != 0) << 1)
                 | ((uint)(av.z != 0) << 2) | ((uint)(av.w != 0) << 3);
        uint v = nib | (__shfl_xor(nib, 1, 64) << 4);
        v = v | (__shfl_xor(v, 2, 64) << 8);
        v = v | (__shfl_xor(v, 4, 64) << 16);
        if ((l & 7) == 0)
            brow[jb * 8 + (l >> 3)] = v;   // word covers j = jb*256 + 4l .. +31
    }
}

// ---------------- Kernel 1: Wh = h @ W, s1 = Wh@a1, s2 = Wh@a2 ----------------
// s1/s2 pre-scaled by 1/ln2 for exp2 in k_attn.
__global__ __launch_bounds__(256) void k_wh(
    const float* __restrict__ h, const float* __restrict__ W,
    const float* __restrict__ a, float* __restrict__ Wh,
    float* __restrict__ s1, float* __restrict__ s2)
{
    __shared__ float hrow[2][FIN];
    __shared__ float rbuf[2][2][2];
    const int t   = threadIdx.x;
    const int rh  = t >> 7;
    const int c   = t & 127;
    const int row = (blockIdx.x << 1) + rh;

    hrow[rh][c]       = h[(size_t)row * FIN + c];
    hrow[rh][c + 128] = h[(size_t)row * FIN + c + 128];
    __syncthreads();

    float acc = 0.f;
    #pragma unroll 8
    for (int k = 0; k < FIN; ++k)
        acc = fmaf(hrow[rh][k], W[k * FOUT + c], acc);

    Wh[(size_t)row * FOUT + c] = acc;

    float p1 = acc * a[c];
    float p2 = acc * a[FOUT + c];
    #pragma unroll
    for (int off = 32; off; off >>= 1) {
        p1 += __shfl_down(p1, off, 64);
        p2 += __shfl_down(p2, off, 64);
    }
    if ((t & 63) == 0) { rbuf[rh][c >> 6][0] = p1; rbuf[rh][c >> 6][1] = p2; }
    __syncthreads();
    if (c == 0) {
        const float k2 = 1.44269504088896f;  // 1/ln2
        s1[row] = (rbuf[rh][0][0] + rbuf[rh][1][0]) * k2;
        s2[row] = (rbuf[rh][0][1] + rbuf[rh][1][1]) * k2;
    }
}

// ---------------- Kernel 2: transpose+convert Wh -> WhT fp16 [128][8192] ------
__global__ __launch_bounds__(256) void k_tr(
    const float* __restrict__ Wh, _Float16* __restrict__ WhT)
{
    __shared__ float tile[64][129];
    const int t = threadIdx.x;
    const int rbase = blockIdx.x * 64;

    #pragma unroll
    for (int q = 0; q < 8; ++q) {
        int i4 = q * 256 + t;
        int r  = i4 >> 5;
        int c4 = (i4 & 31) * 4;
        *(float4*)&tile[r][c4] = *(const float4*)&Wh[(size_t)(rbase + r) * FOUT + c4];
    }
    __syncthreads();

    const int c = t >> 1, half = t & 1;
    _Float16 buf[32];
    #pragma unroll
    for (int r = 0; r < 32; ++r) buf[r] = (_Float16)tile[32 * half + r][c];
    #pragma unroll
    for (int q = 0; q < 4; ++q)
        *(f16x8*)&WhT[(size_t)c * N_ + rbase + 32 * half + 8 * q] = *(f16x8*)&buf[8 * q];
}

// ---------------- Kernel 3: fused masked-softmax numerator (MFMA) -------------
// Grid: 1024 = 256 row-blocks (32 rows) x 4 j-splits (2048 j each).
// Block: 512 thr = 8 waves; wave w owns output cols [16w,16w+16).
// adj comes from the 8 MB bitmask (L2/L3-resident): 1 dword per thread/tile.
__global__ __launch_bounds__(512, 4) void k_attn(
    const uint* __restrict__ bm, const _Float16* __restrict__ WhT,
    const float* __restrict__ s1g, const float* __restrict__ s2g,
    float* __restrict__ num_g, float* __restrict__ den_g)
{
    __shared__ _Float16 pA[2][32][136];   // 17 KB, padded: 272 B row stride
    __shared__ float s2s[2048];           // 8 KB

    const int t  = threadIdx.x;
    const int w  = t >> 6;
    const int l  = t & 63;

    const int rb    = blockIdx.x & 255;
    const int sp    = blockIdx.x >> 8;
    const int rbase = rb * 32;
    const int jbase = sp * 2048;

    // stage s2 slice (8 KB)
    *(float4*)&s2s[t * 4] = *(const float4*)&s2g[jbase + t * 4];

    // p-compute mapping: thread owns row r, 8 j's at j0 = 8g
    const int r  = t >> 4;                 // 0..31
    const int g  = t & 15;                 // j-group
    const int j0 = g << 3;                 // 0..120
    const int shift = (g & 3) * 8;         // bit offset of j0 within its word
    const float s1r = s1g[rbase + r];
    // mask word for (row, tile): brow[tile*4]
    const uint* __restrict__ brow =
        bm + (size_t)(rbase + r) * NW + sp * 64 + (g >> 2);

    // MFMA operand addressing
    const int ln15 = l & 15, lq = l >> 4;
    const _Float16* __restrict__ bptr =
        WhT + (size_t)(16 * w + ln15) * N_ + jbase + 8 * lq;

    f32x4 acc0 = {0.f, 0.f, 0.f, 0.f};
    f32x4 acc1 = {0.f, 0.f, 0.f, 0.f};
    float denp = 0.f;

    // phase-A: 8 attention weights -> fp16 LDS buffer `buf`.
    // p = exp2(lrelu(s1+s2) - 4/ln2); mask bit i of (mv>>shift).
    auto computeP = [&](uint mv, int tile, int buf) {
        const float bias = -5.77078016f;   // -4/ln2
        const uint byte = mv >> shift;
        const float* s2p = &s2s[tile * 128 + j0];
        float4 sA = *(const float4*)(s2p);
        float4 sB = *(const float4*)(s2p + 4);
        float m, e;
        f16x8 pv;
        m = s1r + sA.x; e = fmaxf(m, 0.2f * m); pv[0] = (_Float16)((byte & 1u)   ? __builtin_amdgcn_exp2f(e + bias) : 0.f);
        m = s1r + sA.y; e = fmaxf(m, 0.2f * m); pv[1] = (_Float16)((byte & 2u)   ? __builtin_amdgcn_exp2f(e + bias) : 0.f);
        m = s1r + sA.z; e = fmaxf(m, 0.2f * m); pv[2] = (_Float16)((byte & 4u)   ? __builtin_amdgcn_exp2f(e + bias) : 0.f);
        m = s1r + sA.w; e = fmaxf(m, 0.2f * m); pv[3] = (_Float16)((byte & 8u)   ? __builtin_amdgcn_exp2f(e + bias) : 0.f);
        m = s1r + sB.x; e = fmaxf(m, 0.2f * m); pv[4] = (_Float16)((byte & 16u)  ? __builtin_amdgcn_exp2f(e + bias) : 0.f);
        m = s1r + sB.y; e = fmaxf(m, 0.2f * m); pv[5] = (_Float16)((byte & 32u)  ? __builtin_amdgcn_exp2f(e + bias) : 0.f);
        m = s1r + sB.z; e = fmaxf(m, 0.2f * m); pv[6] = (_Float16)((byte & 64u)  ? __builtin_amdgcn_exp2f(e + bias) : 0.f);
        m = s1r + sB.w; e = fmaxf(m, 0.2f * m); pv[7] = (_Float16)((byte & 128u) ? __builtin_amdgcn_exp2f(e + bias) : 0.f);
        denp += (float)pv[0] + (float)pv[1] + (float)pv[2] + (float)pv[3]
              + (float)pv[4] + (float)pv[5] + (float)pv[6] + (float)pv[7];
        *(f16x8*)&pA[buf][r][j0] = pv;
    };

    // phase-B: 8 MFMAs over one 128-j tile from LDS buffer `buf`
    auto mmaTile = [&](int buf, int jb) {
        f16x8 b0 = *(const f16x8*)(bptr + jb);
        f16x8 b1 = *(const f16x8*)(bptr + jb + 32);
        f16x8 b2 = *(const f16x8*)(bptr + jb + 64);
        f16x8 b3 = *(const f16x8*)(bptr + jb + 96);
        const _Float16* a0p = &pA[buf][ln15][8 * lq];
        const _Float16* a1p = &pA[buf][16 + ln15][8 * lq];
        acc0 = __builtin_amdgcn_mfma_f32_16x16x32_f16(*(const f16x8*)(a0p),      b0, acc0, 0, 0, 0);
        acc1 = __builtin_amdgcn_mfma_f32_16x16x32_f16(*(const f16x8*)(a1p),      b0, acc1, 0, 0, 0);
        acc0 = __builtin_amdgcn_mfma_f32_16x16x32_f16(*(const f16x8*)(a0p + 32), b1, acc0, 0, 0, 0);
        acc1 = __builtin_amdgcn_mfma_f32_16x16x32_f16(*(const f16x8*)(a1p + 32), b1, acc1, 0, 0, 0);
        acc0 = __builtin_amdgcn_mfma_f32_16x16x32_f16(*(const f16x8*)(a0p + 64), b2, acc0, 0, 0, 0);
        acc1 = __builtin_amdgcn_mfma_f32_16x16x32_f16(*(const f16x8*)(a1p + 64), b2, acc1, 0, 0, 0);
        acc0 = __builtin_amdgcn_mfma_f32_16x16x32_f16(*(const f16x8*)(a0p + 96), b3, acc0, 0, 0, 0);
        acc1 = __builtin_amdgcn_mfma_f32_16x16x32_f16(*(const f16x8*)(a1p + 96), b3, acc1, 0, 0, 0);
    };

    // prologue: mask words for tiles 0,1
    uint mv0 = brow[0];
    uint mv1 = brow[4];

    LDS_BARRIER();                   // s2s ready
    computeP(mv0, 0, 0);             // P(0) -> buf0
    LDS_BARRIER();

    // main loop: 14 tiles, explicitly unrolled x2 (one barrier per tile)
    for (int tt = 0; tt < 14; tt += 2) {
        {   // tile tt: read buf0; write P(tt+1)->buf1; refill slot0 w/ tile tt+2
            mv0 = brow[(tt + 2) * 4];
            mmaTile(0, tt * 128);
            computeP(mv1, tt + 1, 1);
            LDS_BARRIER();
        }
        {   // tile tt+1: read buf1; write P(tt+2)->buf0; refill slot1 w/ tile tt+3
            mv1 = brow[(tt + 3) * 4];
            mmaTile(1, (tt + 1) * 128);
            computeP(mv0, tt + 2, 0);
            LDS_BARRIER();
        }
    }
    // epilogue: tiles 14, 15
    mmaTile(0, 14 * 128);
    computeP(mv1, 15, 1);
    LDS_BARRIER();
    mmaTile(1, 15 * 128);

    // ---- den: reduce 16 lanes per row ----
    denp += __shfl_xor(denp, 1, 64);
    denp += __shfl_xor(denp, 2, 64);
    denp += __shfl_xor(denp, 4, 64);
    denp += __shfl_xor(denp, 8, 64);
    if ((t & 15) == 0)
        den_g[(size_t)sp * N_ + rbase + r] = denp;

    // ---- num: unnormalized partial writes ----
    const int colg = 16 * w + ln15;
    const int rq   = lq * 4;
    #pragma unroll
    for (int q = 0; q < 4; ++q) {
        num_g[((size_t)sp * N_ + rbase + rq + q)      * FOUT + colg] = acc0[q];
        num_g[((size_t)sp * N_ + rbase + 16 + rq + q) * FOUT + colg] = acc1[q];
    }
}

// ---------------- Kernel 4: combine j-splits and normalize --------------------
__global__ __launch_bounds__(256) void k_norm(
    const float* __restrict__ num_g, const float* __restrict__ den_g,
    float* __restrict__ out)
{
    const int idx4 = blockIdx.x * 256 + threadIdx.x;
    const int i  = idx4 >> 5;
    const int c4 = (idx4 & 31) * 4;

    float4 s = {0.f, 0.f, 0.f, 0.f};
    float  d = 0.f;
    #pragma unroll
    for (int sp = 0; sp < 4; ++sp) {
        float4 v = *(const float4*)(num_g + ((size_t)sp * N_ + i) * FOUT + c4);
        s.x += v.x; s.y += v.y; s.z += v.z; s.w += v.w;
        d += den_g[(size_t)sp * N_ + i];
    }
    const float inv = 1.f / d;
    float4 o = {s.x * inv, s.y * inv, s.z * inv, s.w * inv};
    *(float4*)&out[(size_t)i * FOUT + c4] = o;
}

extern "C" void kernel_launch(void* const* d_in, const int* in_sizes, int n_in,
                              void* d_out, int out_size, void* d_ws, size_t ws_size,
                              hipStream_t stream) {
    const float* h   = (const float*)d_in[0];
    const int*   adj = (const int*)d_in[1];
    const float* W   = (const float*)d_in[2];
    const float* a   = (const float*)d_in[3];
    float* out = (float*)d_out;

    char* ws = (char*)d_ws;
    float*    Wh  = (float*)ws;                           // 4 MB
    _Float16* WhT = (_Float16*)(ws + (4u << 20));         // 2 MB
    float*    s1  = (float*)(ws + (6u << 20));            // 32 KB
    float*    s2  = (float*)(ws + (6u << 20) + 32768);    // 32 KB
    float*    num = (float*)(ws + (7u << 20));            // 16 MB
    float*    den = (float*)(ws + (23u << 20));           // 128 KB
    uint*     bmk = (uint*)(ws + (24u << 20));            // 8 MB

    k_pack<<<2048,   256, 0, stream>>>(adj, bmk);
    k_wh  <<<N_ / 2, 256, 0, stream>>>(h, W, a, Wh, s1, s2);
    k_tr  <<<N_ / 64, 256, 0, stream>>>(Wh, WhT);
    k_attn<<<1024,  512, 0, stream>>>(bmk, WhT, s1, s2, num, den);
    k_norm<<<1024,  256, 0, stream>>>(num, den, out);
}